// Round 15
// baseline (427.604 us; speedup 1.0000x reference)
//
#include <hip/hip_runtime.h>
#include <math.h>

#define N_NODES 50000
#define N_EDGES 1000000
#define NGRAPH  512
#define INC     39
#define NBKT 196 // dst buckets of 256 nodes
#define BIN_BLK 4096
#define PAIR_C (2*192*64)

typedef __attribute__((ext_vector_type(8))) short bf16x8;
typedef __attribute__((ext_vector_type(4))) float f32x4;
typedef __attribute__((ext_vector_type(4))) int i32x4;

__device__ __forceinline__ float lrelu(float x){ return fmaxf(0.01f*x, x); }
__device__ __forceinline__ float fexp(float x){ return __builtin_amdgcn_exp2f(x*1.4426950408889634f); }
__device__ __forceinline__ float frcp(float x){ return __builtin_amdgcn_rcpf(x); }
__device__ __forceinline__ float eluf (float x){ return x > 0.f ? x : fexp(x) - 1.f; }
__device__ __forceinline__ float sigm (float x){ return frcp(1.f + fexp(-x)); }
__device__ __forceinline__ float ftanh(float x){
  x = fminf(fmaxf(x, -15.f), 15.f);
  float e = __builtin_amdgcn_exp2f(x*2.8853900817779268f); // exp(2x)
  return (e - 1.f)*frcp(e + 1.f);
}
__device__ __forceinline__ float rdlane(float v, int l){
  return __int_as_float(__builtin_amdgcn_readlane(__float_as_int(v), l));
}
__device__ __forceinline__ unsigned pk_bf16(float a, float b){
  unsigned r;
  asm volatile("v_cvt_pk_bf16_f32 %0, %1, %2" : "=v"(r) : "v"(a), "v"(b));
  return r;
}
__device__ __forceinline__ float bl(unsigned p){ return __uint_as_float(p << 16); }
__device__ __forceinline__ float bh(unsigned p){ return __uint_as_float(p & 0xffff0000u); }
__device__ __forceinline__ float tobf16f(float v){ return __uint_as_float(pk_bf16(v, 0.f) << 16); }

// ================= bucket histogram (196 coarse buckets) =================
__global__ __launch_bounds__(256) void k_bhist(const int* __restrict__ dst,
                                               int* __restrict__ bcnt) {
  __shared__ int h[NBKT];
  for (int i = threadIdx.x; i < NBKT; i += 256) h[i] = 0;
  __syncthreads();
  const int e0 = blockIdx.x * BIN_BLK;
  #pragma unroll 4
  for (int u = 0; u < 16; ++u) {
    int e = e0 + u*256 + threadIdx.x;
    if (e < N_EDGES) atomicAdd(&h[dst[e] >> 8], 1);
  }
  __syncthreads();
  for (int i = threadIdx.x; i < NBKT; i += 256) if (h[i]) atomicAdd(&bcnt[i], h[i]);
}

// ===== merged: bucket scan + bcur init + graph bounds =====
__global__ __launch_bounds__(512) void k_setup(const int* __restrict__ bcnt,
                                               int* __restrict__ bstart,
                                               int* __restrict__ bcur,
                                               int* __restrict__ rowptrN,
                                               const int* __restrict__ batch,
                                               int* __restrict__ gstart) {
  __shared__ int s[256];
  const int t = threadIdx.x;
  int v = 0;
  if (t < 256) { v = (t < NBKT) ? bcnt[t] : 0; s[t] = v; }
  __syncthreads();
  for (int off = 1; off < 256; off <<= 1) {
    int x = (t >= off && t < 256) ? s[t-off] : 0;
    __syncthreads();
    if (t < 256) s[t] += x;
    __syncthreads();
  }
  if (t < NBKT) { int st = s[t] - v; bstart[t] = st; bcur[t] = st; }
  if (t == 0) { bstart[NBKT] = N_EDGES; rowptrN[0] = N_EDGES; }
  int g = t;
  int lo = 0, hi = N_NODES;
  while (lo < hi) { int mid = (lo+hi)>>1; if (batch[mid] < g) lo = mid+1; else hi = mid; }
  gstart[g] = lo;
  if (g == 0) gstart[NGRAPH] = N_NODES;
}

// ===== Pass A: bin edges into 196 coarse buckets =====
__global__ __launch_bounds__(1024) void k_binA(const int* __restrict__ dst,
                                               const int* __restrict__ src,
                                               const float* __restrict__ p,
                                               int* __restrict__ bcur,
                                               int2* __restrict__ binned) {
  __shared__ int lcnt[NBKT];
  __shared__ int lbase[NBKT];
  __shared__ int gbase[NBKT];
  __shared__ int tmp[256];
  __shared__ int totsh;
  __shared__ int2 stage[BIN_BLK];
  const int t = threadIdx.x;
  const int e0 = blockIdx.x * BIN_BLK;
  for (int i = t; i < NBKT; i += 1024) lcnt[i] = 0;
  __syncthreads();
  int myb[4], myr[4], myd[4], mys[4]; float myp[4];
  #pragma unroll
  for (int u = 0; u < 4; ++u) {
    int e = e0 + u*1024 + t;
    if (e < N_EDGES) {
      int d = dst[e];
      myd[u] = d; mys[u] = src[e]; myp[u] = p[e];
      int b = d >> 8;
      myb[u] = b;
      myr[u] = atomicAdd(&lcnt[b], 1);
    } else myb[u] = -1;
  }
  __syncthreads();
  if (t < 256) tmp[t] = (t < NBKT) ? lcnt[t] : 0;
  __syncthreads();
  for (int off = 1; off < 256; off <<= 1) {
    int v = (t >= off && t < 256) ? tmp[t-off] : 0;
    __syncthreads();
    if (t < 256) tmp[t] += v;
    __syncthreads();
  }
  if (t < NBKT) lbase[t] = tmp[t] - lcnt[t];
  if (t == NBKT-1) totsh = tmp[t];
  if (t < NBKT && lcnt[t] > 0) gbase[t] = atomicAdd(&bcur[t], lcnt[t]);
  __syncthreads();
  #pragma unroll
  for (int u = 0; u < 4; ++u) {
    if (myb[u] >= 0) {
      int x = (mys[u] & 0xffff) | ((myd[u] & 255) << 16) | (myb[u] << 24);
      stage[lbase[myb[u]] + myr[u]] = make_int2(x, __float_as_int(myp[u]));
    }
  }
  __syncthreads();
  const int tot = totsh;
  for (int i = t; i < tot; i += 1024) {
    int2 r = stage[i];
    int b = (unsigned)r.x >> 24;
    binned[gbase[b] + (i - lbase[b])] = r;
  }
}

// ===== Pass B: per-bucket two-pass — build rowptr AND final CSR order =====
__global__ __launch_bounds__(1024) void k_binB(const int* __restrict__ bstart,
                                               const int2* __restrict__ binned,
                                               int2* __restrict__ sorted,
                                               int* __restrict__ rowptr) {
  __shared__ int lcnt[256];
  __shared__ int loc[256];
  const int b = blockIdx.x;
  const int base = bstart[b], end = bstart[b+1];
  const int t = threadIdx.x;
  if (t < 256) lcnt[t] = 0;
  __syncthreads();
  for (int i = base + t; i < end; i += 1024)
    atomicAdd(&lcnt[(binned[i].x >> 16) & 255], 1);
  __syncthreads();
  if (t < 256) loc[t] = lcnt[t];
  __syncthreads();
  for (int off = 1; off < 256; off <<= 1) {
    int v = (t >= off && t < 256) ? loc[t-off] : 0;
    __syncthreads();
    if (t < 256) loc[t] += v;
    __syncthreads();
  }
  if (t < 256) {
    int st = base + loc[t] - lcnt[t];
    loc[t] = st;
    int node = b*256 + t;
    if (node < N_NODES) rowptr[node] = st;
    lcnt[t] = 0;
  }
  __syncthreads();
  for (int i = base + t; i < end; i += 1024) {
    int2 r = binned[i];
    int dlow = (r.x >> 16) & 255;
    int rank = atomicAdd(&lcnt[dlow], 1);
    sorted[loc[dlow] + rank] = r;
  }
}

// ================= bf16 weight prepack: 4 GRU pairs in one launch =================
__global__ __launch_bounds__(256) void k_wpack4(const float* __restrict__ a0, const float* __restrict__ b0,
                                                const float* __restrict__ a1, const float* __restrict__ b1,
                                                const float* __restrict__ a2, const float* __restrict__ b2,
                                                const float* __restrict__ a3, const float* __restrict__ b3,
                                                unsigned short* __restrict__ o) {
  int i = blockIdx.x*256 + threadIdx.x;
  if (i >= 4*PAIR_C) return;
  int pair = i / PAIR_C;
  int r = i - pair*PAIR_C;
  bool hi = r >= 192*64;
  int rr = hi ? r - 192*64 : r;
  const float* s;
  if      (pair == 0) s = hi ? b0 : a0;
  else if (pair == 1) s = hi ? b1 : a1;
  else if (pair == 2) s = hi ? b2 : a2;
  else                s = hi ? b3 : a3;
  o[i] = (unsigned short)(pk_bf16(s[rr], 0.f) & 0xffffu);
}

// ===== MFMA lin1: wave = 16 nodes, K=39 padded; x split hi/lo bf16 =====
__global__ __launch_bounds__(256) void k_lin1M(const float* __restrict__ x,
                                               const float* __restrict__ W,  // [64][39]
                                               const float* __restrict__ b,
                                               const float* __restrict__ v1,
                                               float* __restrict__ out,
                                               float* __restrict__ o1) {
  const int lane = threadIdx.x & 63;
  const int l15 = lane & 15, lg = lane >> 4;
  const int n0 = blockIdx.x*64 + (threadIdx.x >> 6)*16;
  if (n0 >= N_NODES) return;
  union BF { bf16x8 v; unsigned u[4]; };
  BF Bf[3][4];
  #pragma unroll
  for (int c = 0; c < 3; ++c) {
    int kv0 = c*32 + lg*8;
    int off = (kv0 < 48) ? kv0 : (kv0 - 48);
    int cnt = 39 - off; cnt = cnt < 0 ? 0 : (cnt > 8 ? 8 : cnt);
    #pragma unroll
    for (int ct = 0; ct < 4; ++ct) {
      const float* wrow = W + (ct*16 + l15)*INC;
      float w8[8];
      #pragma unroll
      for (int j = 0; j < 8; ++j) w8[j] = (j < cnt) ? wrow[off+j] : 0.f;
      Bf[c][ct].u[0] = pk_bf16(w8[0], w8[1]);
      Bf[c][ct].u[1] = pk_bf16(w8[2], w8[3]);
      Bf[c][ct].u[2] = pk_bf16(w8[4], w8[5]);
      Bf[c][ct].u[3] = pk_bf16(w8[6], w8[7]);
    }
  }
  const int arow = n0 + l15;
  const bool av = arow < N_NODES;
  const float* xrow = x + (size_t)arow*INC;
  BF A[3];
  #pragma unroll
  for (int c = 0; c < 3; ++c) {
    int kv0 = c*32 + lg*8;
    int islo = (kv0 >= 48);
    int off = islo ? (kv0 - 48) : kv0;
    int cnt = 39 - off; cnt = cnt < 0 ? 0 : (cnt > 8 ? 8 : cnt);
    float a8[8];
    #pragma unroll
    for (int j = 0; j < 8; ++j) {
      float v = (av && j < cnt) ? xrow[off+j] : 0.f;
      if (islo) v = v - tobf16f(v);
      a8[j] = v;
    }
    A[c].u[0] = pk_bf16(a8[0], a8[1]);
    A[c].u[1] = pk_bf16(a8[2], a8[3]);
    A[c].u[2] = pk_bf16(a8[4], a8[5]);
    A[c].u[3] = pk_bf16(a8[6], a8[7]);
  }
  f32x4 acc[4];
  #pragma unroll
  for (int ct = 0; ct < 4; ++ct) acc[ct] = (f32x4){0.f,0.f,0.f,0.f};
  #pragma unroll
  for (int c = 0; c < 3; ++c)
    #pragma unroll
    for (int ct = 0; ct < 4; ++ct)
      acc[ct] = __builtin_amdgcn_mfma_f32_16x16x32_bf16(A[c].v, Bf[c][ct].v, acc[ct], 0, 0, 0);
  float bb[4], attv[4];
  #pragma unroll
  for (int ct = 0; ct < 4; ++ct) { bb[ct] = b[ct*16+l15]; attv[ct] = v1[ct*16+l15]; }
  #pragma unroll
  for (int reg = 0; reg < 4; ++reg) {
    const int node = n0 + 4*lg + reg;
    const bool nv = node < N_NODES;
    float pr = 0.f;
    #pragma unroll
    for (int ct = 0; ct < 4; ++ct) {
      float val = lrelu(acc[ct][reg] + bb[ct]);
      if (nv) out[(size_t)node*64 + ct*16 + l15] = val;
      pr = fmaf(val, attv[ct], pr);
    }
    pr += __shfl_xor(pr, 1, 64);
    pr += __shfl_xor(pr, 2, 64);
    pr += __shfl_xor(pr, 4, 64);
    pr += __shfl_xor(pr, 8, 64);
    if (l15 == 0 && nv) o1[node] = pr;
  }
}

// ===== MFMA dual matmul: u paired-dword layout + y packed =====
__global__ __launch_bounds__(256) void k_mmdualM(const float* __restrict__ in,
                                                 const float* __restrict__ W1, // [64][80]
                                                 const float* __restrict__ W2, // [64][64]
                                                 uint2* __restrict__ ubf2,     // N*16 uint2
                                                 unsigned* __restrict__ ypk, int R) {
  const int lane = threadIdx.x & 63;
  const int l15 = lane & 15, lg = lane >> 4;
  const int n0 = blockIdx.x*64 + (threadIdx.x >> 6)*16;
  if (n0 >= R) return;
  union BF { bf16x8 v; unsigned u[4]; };
  BF B1[4][2], B2[4][2];
  #pragma unroll
  for (int ct = 0; ct < 4; ++ct) {
    #pragma unroll
    for (int c = 0; c < 2; ++c) {
      const float* w1 = W1 + (size_t)(ct*16 + l15)*80 + c*32 + lg*8;
      const float* w2 = W2 + (size_t)(ct*16 + l15)*64 + c*32 + lg*8;
      B1[ct][c].u[0] = pk_bf16(w1[0], w1[1]);
      B1[ct][c].u[1] = pk_bf16(w1[2], w1[3]);
      B1[ct][c].u[2] = pk_bf16(w1[4], w1[5]);
      B1[ct][c].u[3] = pk_bf16(w1[6], w1[7]);
      B2[ct][c].u[0] = pk_bf16(w2[0], w2[1]);
      B2[ct][c].u[1] = pk_bf16(w2[2], w2[3]);
      B2[ct][c].u[2] = pk_bf16(w2[4], w2[5]);
      B2[ct][c].u[3] = pk_bf16(w2[6], w2[7]);
    }
  }
  const int arow = n0 + l15;
  const bool av = arow < R;
  const float* xr = in + (size_t)arow*64;
  BF A[2];
  #pragma unroll
  for (int c = 0; c < 2; ++c) {
    const int k0 = c*32 + lg*8;
    float4 v0, v1;
    if (av) { v0 = *(const float4*)&xr[k0]; v1 = *(const float4*)&xr[k0+4]; }
    else    { v0 = v1 = make_float4(0.f,0.f,0.f,0.f); }
    A[c].u[0] = pk_bf16(v0.x, v0.y);
    A[c].u[1] = pk_bf16(v0.z, v0.w);
    A[c].u[2] = pk_bf16(v1.x, v1.y);
    A[c].u[3] = pk_bf16(v1.z, v1.w);
  }
  f32x4 aU[4], aY[4];
  #pragma unroll
  for (int ct = 0; ct < 4; ++ct) { aU[ct] = (f32x4){0.f,0.f,0.f,0.f}; aY[ct] = (f32x4){0.f,0.f,0.f,0.f}; }
  #pragma unroll
  for (int c = 0; c < 2; ++c)
    #pragma unroll
    for (int ct = 0; ct < 4; ++ct) {
      aU[ct] = __builtin_amdgcn_mfma_f32_16x16x32_bf16(A[c].v, B1[ct][c].v, aU[ct], 0, 0, 0);
      aY[ct] = __builtin_amdgcn_mfma_f32_16x16x32_bf16(A[c].v, B2[ct][c].v, aY[ct], 0, 0, 0);
    }
  #pragma unroll
  for (int reg = 0; reg < 4; ++reg) {
    const int node = n0 + 4*lg + reg;
    const bool nv = node < R;
    if (nv) {
      ubf2[(size_t)node*16 + l15] = make_uint2(pk_bf16(aU[0][reg], aU[2][reg]),
                                               pk_bf16(aU[1][reg], aU[3][reg]));
    }
    #pragma unroll
    for (int ct = 0; ct < 4; ++ct) {
      float yy = aY[ct][reg];
      float yp = __shfl_xor(yy, 1, 64);
      if (!(l15 & 1) && nv)
        ypk[(unsigned)node*32 + ct*8 + (l15>>1)] = pk_bf16(yy, yp);
    }
  }
}

// ===== MFMA mm64: [R,64]@W.T; optional fp32/packed out + dual dots; hilo for fp32-grade =====
__global__ __launch_bounds__(256) void k_mm64M(const float* __restrict__ in,
                                               const float* __restrict__ W, int rs,
                                               float* __restrict__ out,
                                               unsigned* __restrict__ outp, int R,
                                               const float* __restrict__ v1,
                                               const float* __restrict__ v2,
                                               float* __restrict__ o1,
                                               float* __restrict__ o2, int hilo) {
  const int lane = threadIdx.x & 63;
  const int l15 = lane & 15, lg = lane >> 4;
  const int n0 = blockIdx.x*64 + (threadIdx.x >> 6)*16;
  if (n0 >= R) return;
  union BF { bf16x8 v; unsigned u[4]; };
  BF Bf[4][2];
  #pragma unroll
  for (int ct = 0; ct < 4; ++ct) {
    #pragma unroll
    for (int c = 0; c < 2; ++c) {
      const float* w = W + (size_t)(ct*16 + l15)*rs + c*32 + lg*8;
      Bf[ct][c].u[0] = pk_bf16(w[0], w[1]);
      Bf[ct][c].u[1] = pk_bf16(w[2], w[3]);
      Bf[ct][c].u[2] = pk_bf16(w[4], w[5]);
      Bf[ct][c].u[3] = pk_bf16(w[6], w[7]);
    }
  }
  const int arow = n0 + l15;
  const bool av = arow < R;
  const float* xr = in + (size_t)arow*64;
  BF A[2], Alo[2];
  #pragma unroll
  for (int c = 0; c < 2; ++c) {
    const int k0 = c*32 + lg*8;
    float f[8];
    if (av) {
      float4 v0 = *(const float4*)&xr[k0];
      float4 v1l = *(const float4*)&xr[k0+4];
      f[0]=v0.x; f[1]=v0.y; f[2]=v0.z; f[3]=v0.w;
      f[4]=v1l.x; f[5]=v1l.y; f[6]=v1l.z; f[7]=v1l.w;
    } else {
      #pragma unroll
      for (int j = 0; j < 8; ++j) f[j] = 0.f;
    }
    A[c].u[0] = pk_bf16(f[0], f[1]);
    A[c].u[1] = pk_bf16(f[2], f[3]);
    A[c].u[2] = pk_bf16(f[4], f[5]);
    A[c].u[3] = pk_bf16(f[6], f[7]);
    if (hilo) {
      float l[8];
      #pragma unroll
      for (int j = 0; j < 8; ++j) l[j] = f[j] - tobf16f(f[j]);
      Alo[c].u[0] = pk_bf16(l[0], l[1]);
      Alo[c].u[1] = pk_bf16(l[2], l[3]);
      Alo[c].u[2] = pk_bf16(l[4], l[5]);
      Alo[c].u[3] = pk_bf16(l[6], l[7]);
    }
  }
  f32x4 acc[4];
  #pragma unroll
  for (int ct = 0; ct < 4; ++ct) acc[ct] = (f32x4){0.f,0.f,0.f,0.f};
  #pragma unroll
  for (int c = 0; c < 2; ++c)
    #pragma unroll
    for (int ct = 0; ct < 4; ++ct) {
      acc[ct] = __builtin_amdgcn_mfma_f32_16x16x32_bf16(A[c].v, Bf[ct][c].v, acc[ct], 0, 0, 0);
      if (hilo)
        acc[ct] = __builtin_amdgcn_mfma_f32_16x16x32_bf16(Alo[c].v, Bf[ct][c].v, acc[ct], 0, 0, 0);
    }
  float v1v[4], v2v[4];
  #pragma unroll
  for (int ct = 0; ct < 4; ++ct) {
    v1v[ct] = v1 ? v1[ct*16+l15] : 0.f;
    v2v[ct] = v2 ? v2[ct*16+l15] : 0.f;
  }
  #pragma unroll
  for (int reg = 0; reg < 4; ++reg) {
    const int node = n0 + 4*lg + reg;
    const bool nv = node < R;
    float pr1 = 0.f, pr2 = 0.f;
    #pragma unroll
    for (int ct = 0; ct < 4; ++ct) {
      float val = acc[ct][reg];
      if (out && nv) out[(size_t)node*64 + ct*16 + l15] = val;
      if (outp) {
        float partner = __shfl_xor(val, 1, 64);
        if (!(l15 & 1) && nv) outp[(unsigned)node*32 + ct*8 + (l15>>1)] = pk_bf16(val, partner);
      }
      pr1 = fmaf(val, v1v[ct], pr1);
      pr2 = fmaf(val, v2v[ct], pr2);
    }
    if (o1) {
      pr1 += __shfl_xor(pr1, 1, 64); pr2 += __shfl_xor(pr2, 1, 64);
      pr1 += __shfl_xor(pr1, 2, 64); pr2 += __shfl_xor(pr2, 2, 64);
      pr1 += __shfl_xor(pr1, 4, 64); pr2 += __shfl_xor(pr2, 4, 64);
      pr1 += __shfl_xor(pr1, 8, 64); pr2 += __shfl_xor(pr2, 8, 64);
      if (l15 == 0 && nv) { o1[node] = pr1; if (o2) o2[node] = pr2; }
    }
  }
}

// ===== GATE edge scores: wave = 16 edges (1 MFMA tile) for max TLP =====
__global__ __launch_bounds__(256) void k_escore(const int* __restrict__ srcarr,
                                                const float* __restrict__ ea,
                                                const float* __restrict__ glin1, // [64][80]
                                                const float* __restrict__ attl,
                                                const uint2* __restrict__ ubf2,
                                                float* __restrict__ pout) {
  const int lane = threadIdx.x & 63;
  const int l15 = lane & 15, lg = lane >> 4;
  const int gw = blockIdx.x*4 + (threadIdx.x >> 6);   // tile index, 16 edges each
  if (gw >= N_EDGES/16) return;
  const int i0 = gw*16;
  // issue all loads up front
  const i32x4 sv = *(const i32x4*)&srcarr[i0 + 4*lg];
  const f32x4 a  = __builtin_nontemporal_load((const f32x4*)&ea[(size_t)(i0 + l15)*16 + lg*4]);
  uint2 ug[4];
  #pragma unroll
  for (int r = 0; r < 4; ++r) ug[r] = ubf2[(size_t)sv[r]*16 + l15];
  float attlv[4];
  unsigned Bu[4][2];
  #pragma unroll
  for (int c = 0; c < 4; ++c) {
    const float4 b = *(const float4*)&glin1[(c*16 + l15)*80 + 64 + lg*4];
    Bu[c][0] = pk_bf16(b.x, b.y);
    Bu[c][1] = pk_bf16(b.z, b.w);
    attlv[c] = attl[c*16 + l15];
  }
  union { bf16x8 v; unsigned u[4]; } A;
  A.u[0] = pk_bf16(a[0], a[1]);
  A.u[1] = pk_bf16(a[2], a[3]);
  A.u[2] = 0; A.u[3] = 0;
  float p[4] = {0.f,0.f,0.f,0.f};
  #pragma unroll
  for (int c = 0; c < 4; ++c) {
    union { bf16x8 v; unsigned u[4]; } B;
    B.u[0] = Bu[c][0]; B.u[1] = Bu[c][1]; B.u[2] = 0; B.u[3] = 0;
    f32x4 z = {0.f,0.f,0.f,0.f};
    f32x4 acc = __builtin_amdgcn_mfma_f32_16x16x32_bf16(A.v, B.v, z, 0, 0, 0);
    #pragma unroll
    for (int r = 0; r < 4; ++r) {
      float uu = (c == 0) ? bl(ug[r].x) : (c == 1) ? bl(ug[r].y)
               : (c == 2) ? bh(ug[r].x) : bh(ug[r].y);
      float t = lrelu(uu + acc[r]);
      p[r] = fmaf(t, attlv[c], p[r]);
    }
  }
  #pragma unroll
  for (int r = 0; r < 4; ++r) {
    p[r] += __shfl_xor(p[r], 1, 64);
    p[r] += __shfl_xor(p[r], 2, 64);
    p[r] += __shfl_xor(p[r], 4, 64);
    p[r] += __shfl_xor(p[r], 8, 64);
  }
  if (l15 == 0) {
    f32x4 o = {p[0], p[1], p[2], p[3]};
    __builtin_nontemporal_store(o, (f32x4*)&pout[i0 + 4*lg]);
  }
}

// ===== GATE aggregation: sorted records {src|dlow|bkt, p}, bf16-packed y gathers =====
__global__ __launch_bounds__(256) void k_gate_agg(const int* __restrict__ rowptr,
                                                  const int2* __restrict__ sorted,
                                                  const float* __restrict__ xr,
                                                  const unsigned* __restrict__ ypk,
                                                  float* __restrict__ hagg) {
  __shared__ int   sS[4][64];
  __shared__ float sE[4][64];
  const int w = __builtin_amdgcn_readfirstlane(threadIdx.x >> 6);
  const int lane = threadIdx.x & 63;
  const int slot = lane >> 5, l2 = lane & 31;
  const int d = blockIdx.x*4 + w;
  const int r0 = __builtin_amdgcn_readfirstlane(rowptr[d]);
  const int r1 = __builtin_amdgcn_readfirstlane(rowptr[d+1]);
  const float xrd = xr[d];
  float accx = 0.f, accy = 0.f, ssum = 0.f;
  for (int base = r0; base < r1; base += 64) {
    int i = base + lane;
    int cnt = r1 - base; if (cnt > 64) cnt = 64;
    float ev = 0.f; int s = 0;
    if (i < r1) {
      int2 r = sorted[i];
      s = r.x & 0xffff;
      ev = fexp(lrelu(__int_as_float(r.y) + xrd));
    }
    sS[w][lane] = s; sE[w][lane] = ev;
    ssum += ev;
    for (int jb = 0; jb < cnt; jb += 16) {
      float e8[8]; unsigned p8[8];
      #pragma unroll
      for (int u = 0; u < 8; ++u) {
        int jj = jb + 2*u + slot;
        int svv; float evv;
        if (jj < cnt) { svv = sS[w][jj]; evv = sE[w][jj]; }
        else          { svv = 0; evv = 0.f; }
        e8[u] = evv;
        p8[u] = ypk[(size_t)svv*32 + l2];
      }
      #pragma unroll
      for (int u = 0; u < 8; ++u) {
        accx = fmaf(e8[u], bl(p8[u]), accx);
        accy = fmaf(e8[u], bh(p8[u]), accy);
      }
    }
  }
  #pragma unroll
  for (int sh = 32; sh > 0; sh >>= 1) ssum += __shfl_xor(ssum, sh, 64);
  accx += __shfl_xor(accx, 32, 64);
  accy += __shfl_xor(accy, 32, 64);
  float rs = frcp(ssum + 1e-16f);
  if (slot == 0) *(float2*)&hagg[d*64 + 2*l2] = make_float2(accx*rs, accy*rs);
}

// ===== GATConv fused: 2 edges per wave, bf16-packed hs, sorted src =====
__global__ __launch_bounds__(256) void k_conv_fused(const int* __restrict__ rowptr,
                                                    const int2* __restrict__ sorted,
                                                    const float* __restrict__ asn,
                                                    const float* __restrict__ adn,
                                                    const unsigned* __restrict__ hsb,
                                                    float* __restrict__ hagg) {
  __shared__ int   sS[4][64];
  __shared__ float sE[4][64];
  const int w = __builtin_amdgcn_readfirstlane(threadIdx.x >> 6);
  const int lane = threadIdx.x & 63;
  const int slot = lane >> 5, l2 = lane & 31;
  const int d = blockIdx.x*4 + w;
  const int r0 = __builtin_amdgcn_readfirstlane(rowptr[d]);
  const int r1 = __builtin_amdgcn_readfirstlane(rowptr[d+1]);
  float adnd = adn[d];
  float accx = 0.f, accy = 0.f, ssum = 0.f;
  for (int base = r0; base < r1; base += 64) {
    int i = base + lane;
    int cnt = r1 - base; if (cnt > 64) cnt = 64;
    float ev = 0.f; int s = 0;
    if (i < r1) { s = sorted[i].x & 0xffff; ev = fexp(lrelu(asn[s] + adnd)); }
    sS[w][lane] = s; sE[w][lane] = ev;
    ssum += ev;
    for (int jb = 0; jb < cnt; jb += 16) {
      float e8[8]; unsigned p8[8];
      #pragma unroll
      for (int u = 0; u < 8; ++u) {
        int jj = jb + 2*u + slot;
        int svv; float evv;
        if (jj < cnt) { svv = sS[w][jj]; evv = sE[w][jj]; }
        else          { svv = 0; evv = 0.f; }
        e8[u] = evv;
        p8[u] = hsb[(size_t)svv*32 + l2];
      }
      #pragma unroll
      for (int u = 0; u < 8; ++u) {
        accx = fmaf(e8[u], bl(p8[u]), accx);
        accy = fmaf(e8[u], bh(p8[u]), accy);
      }
    }
  }
  #pragma unroll
  for (int sh = 32; sh > 0; sh >>= 1) ssum += __shfl_xor(ssum, sh, 64);
  accx += __shfl_xor(accx, 32, 64);
  accy += __shfl_xor(accy, 32, 64);
  float rs = frcp(ssum + 1e-16f);
  if (slot == 0) *(float2*)&hagg[d*64 + 2*l2] = make_float2(accx*rs, accy*rs);
}

// ===== MFMA GRU: out = relu(GRU(elu(inp+pbias), hid)), wave = 16 nodes =====
__global__ __launch_bounds__(256) void k_gruM(const float* __restrict__ inp,
                                              const float* __restrict__ pbias,
                                              const float* __restrict__ hid,
                                              const unsigned short* __restrict__ wibf,
                                              const unsigned short* __restrict__ whbf,
                                              const float* __restrict__ bi,
                                              const float* __restrict__ bh2,
                                              float* __restrict__ out, int R) {
  const int lane = threadIdx.x & 63;
  const int l15 = lane & 15, lg = lane >> 4;
  const int n0 = blockIdx.x*64 + (threadIdx.x >> 6)*16;
  if (n0 >= R) return;
  union BF { bf16x8 v; unsigned u[4]; };
  BF Ai[2], Ah[2];
  const int arow = n0 + l15;
  const bool av = arow < R;
  const float* ibase = inp + (size_t)arow*64;
  const float* hbase = hid + (size_t)arow*64;
  #pragma unroll
  for (int c = 0; c < 2; ++c) {
    const int k0 = c*32 + lg*8;
    float4 p0 = *(const float4*)&pbias[k0];
    float4 p1 = *(const float4*)&pbias[k0+4];
    float4 v0, v1, h0, h1;
    if (av) {
      v0 = *(const float4*)&ibase[k0];   v1 = *(const float4*)&ibase[k0+4];
      h0 = *(const float4*)&hbase[k0];   h1 = *(const float4*)&hbase[k0+4];
    } else {
      v0 = v1 = h0 = h1 = make_float4(0.f,0.f,0.f,0.f);
      p0 = p1 = make_float4(0.f,0.f,0.f,0.f);
    }
    Ai[c].u[0] = pk_bf16(eluf(v0.x+p0.x), eluf(v0.y+p0.y));
    Ai[c].u[1] = pk_bf16(eluf(v0.z+p0.z), eluf(v0.w+p0.w));
    Ai[c].u[2] = pk_bf16(eluf(v1.x+p1.x), eluf(v1.y+p1.y));
    Ai[c].u[3] = pk_bf16(eluf(v1.z+p1.z), eluf(v1.w+p1.w));
    Ah[c].u[0] = pk_bf16(h0.x, h0.y);
    Ah[c].u[1] = pk_bf16(h0.z, h0.w);
    Ah[c].u[2] = pk_bf16(h1.x, h1.y);
    Ah[c].u[3] = pk_bf16(h1.z, h1.w);
  }
  f32x4 rz[8], ni[4], nh[4];
  #pragma unroll
  for (int t = 0; t < 8; ++t) rz[t] = (f32x4){0.f,0.f,0.f,0.f};
  #pragma unroll
  for (int t = 0; t < 4; ++t) { ni[t] = (f32x4){0.f,0.f,0.f,0.f}; nh[t] = (f32x4){0.f,0.f,0.f,0.f}; }
  #pragma unroll
  for (int t = 0; t < 12; ++t) {
    BF Bi0, Bi1, Bh0, Bh1;
    const size_t off = ((size_t)(t*16 + l15))*64 + lg*8;
    Bi0.v = *(const bf16x8*)&wibf[off];
    Bi1.v = *(const bf16x8*)&wibf[off + 32];
    Bh0.v = *(const bf16x8*)&whbf[off];
    Bh1.v = *(const bf16x8*)&whbf[off + 32];
    if (t < 8) {
      f32x4 a = rz[t];
      a = __builtin_amdgcn_mfma_f32_16x16x32_bf16(Ai[0].v, Bi0.v, a, 0, 0, 0);
      a = __builtin_amdgcn_mfma_f32_16x16x32_bf16(Ai[1].v, Bi1.v, a, 0, 0, 0);
      a = __builtin_amdgcn_mfma_f32_16x16x32_bf16(Ah[0].v, Bh0.v, a, 0, 0, 0);
      a = __builtin_amdgcn_mfma_f32_16x16x32_bf16(Ah[1].v, Bh1.v, a, 0, 0, 0);
      rz[t] = a;
    } else {
      f32x4 a = ni[t-8];
      a = __builtin_amdgcn_mfma_f32_16x16x32_bf16(Ai[0].v, Bi0.v, a, 0, 0, 0);
      a = __builtin_amdgcn_mfma_f32_16x16x32_bf16(Ai[1].v, Bi1.v, a, 0, 0, 0);
      ni[t-8] = a;
      f32x4 b = nh[t-8];
      b = __builtin_amdgcn_mfma_f32_16x16x32_bf16(Ah[0].v, Bh0.v, b, 0, 0, 0);
      b = __builtin_amdgcn_mfma_f32_16x16x32_bf16(Ah[1].v, Bh1.v, b, 0, 0, 0);
      nh[t-8] = b;
    }
  }
  float bsum[8], binv[4], bhnv[4];
  #pragma unroll
  for (int t = 0; t < 8; ++t) bsum[t] = bi[t*16+l15] + bh2[t*16+l15];
  #pragma unroll
  for (int t = 0; t < 4; ++t) {
    binv[t] = bi[128 + t*16 + l15];
    bhnv[t] = bh2[128 + t*16 + l15];
  }
  #pragma unroll
  for (int reg = 0; reg < 4; ++reg) {
    const int node = n0 + 4*lg + reg;
    if (node >= R) continue;
    #pragma unroll
    for (int tt = 0; tt < 4; ++tt) {
      float r  = sigm(rz[tt][reg] + bsum[tt]);
      float z  = sigm(rz[4+tt][reg] + bsum[4+tt]);
      float nn = ftanh(ni[tt][reg] + binv[tt] + r*(nh[tt][reg] + bhnv[tt]));
      float hh = hid[(size_t)node*64 + tt*16 + l15];
      float o  = (1.f - z)*nn + z*hh;
      out[(size_t)node*64 + tt*16 + l15] = fmaxf(o, 0.f);
    }
  }
}

// ================= molecule readout, split-K (8 slices per graph) =================
__global__ __launch_bounds__(256) void k_molsum_p(const int* __restrict__ gstart,
                                                  const float* __restrict__ x,
                                                  float* __restrict__ part) {
  int idx = blockIdx.x*4 + (threadIdx.x>>6);
  if (idx >= NGRAPH*8) return;
  int g = idx >> 3, sl = idx & 7;
  int lane = threadIdx.x & 63;
  int n0 = gstart[g], n1 = gstart[g+1];
  int len = n1 - n0;
  int b0 = n0 + (len*sl >> 3), b1 = n0 + (len*(sl+1) >> 3);
  float acc = 0.f;
  for (int n = b0; n < b1; ++n) acc += x[n*64+lane];
  part[idx*64+lane] = acc;
}

__global__ __launch_bounds__(256) void k_molsum_c(const float* __restrict__ part,
                                                  float* __restrict__ outg) {
  int g = blockIdx.x*4 + (threadIdx.x>>6);
  if (g >= NGRAPH) return;
  int lane = threadIdx.x & 63;
  float a = 0.f;
  #pragma unroll
  for (int s = 0; s < 8; ++s) a += part[(g*8+s)*64+lane];
  outg[g*64+lane] = fmaxf(a, 0.f);
}

__global__ __launch_bounds__(256) void k_molhd(const float* __restrict__ outg,
                                               const float* __restrict__ W,
                                               const float* __restrict__ attd,
                                               float* __restrict__ addg) {
  __shared__ float wl[64*65];
  for (int idx = threadIdx.x; idx < 4096; idx += 256) wl[(idx>>6)*65+(idx&63)] = W[idx];
  __syncthreads();
  int g = blockIdx.x*4 + (threadIdx.x>>6);
  if (g >= NGRAPH) return;
  int lane = threadIdx.x & 63;
  float og = outg[g*64+lane];
  float hd = 0.f;
  #pragma unroll
  for (int k = 0; k < 64; ++k) hd += rdlane(og, k) * wl[lane*65+k];
  float p = hd * attd[lane];
  #pragma unroll
  for (int sh = 32; sh > 0; sh >>= 1) p += __shfl_xor(p, sh, 64);
  if (lane == 0) addg[g] = p;
}

__global__ __launch_bounds__(256) void k_molp(const int* __restrict__ gstart,
                                              const float* __restrict__ addg,
                                              const float* __restrict__ asn,
                                              const float* __restrict__ y,
                                              float* __restrict__ part_acc,
                                              float* __restrict__ part_ss) {
  int idx = blockIdx.x*4 + (threadIdx.x>>6);
  if (idx >= NGRAPH*8) return;
  int g = idx >> 3, sl = idx & 7;
  int lane = threadIdx.x & 63;
  int n0 = gstart[g], n1 = gstart[g+1];
  int len = n1 - n0;
  int b0 = n0 + (len*sl >> 3), b1 = n0 + (len*(sl+1) >> 3);
  float adg = addg[g];
  float acc = 0.f, ss = 0.f;
  for (int n = b0; n < b1; ++n) {
    float ev = fexp(lrelu(asn[n] + adg));
    acc += ev * y[n*64+lane];
    ss  += ev;
  }
  part_acc[idx*64+lane] = acc;
  if (lane == 0) part_ss[idx] = ss;
}

__global__ __launch_bounds__(256) void k_molc(const float* __restrict__ part_acc,
                                              const float* __restrict__ part_ss,
                                              float* __restrict__ hg) {
  int g = blockIdx.x*4 + (threadIdx.x>>6);
  if (g >= NGRAPH) return;
  int lane = threadIdx.x & 63;
  float a = 0.f, ss = 0.f;
  #pragma unroll
  for (int s = 0; s < 8; ++s) {
    a  += part_acc[(g*8+s)*64+lane];
    ss += part_ss[g*8+s];
  }
  hg[g*64+lane] = a * frcp(ss + 1e-16f);
}

__global__ __launch_bounds__(128) void k_final(const float* __restrict__ outg,
                                               const float* __restrict__ W,
                                               const float* __restrict__ b,
                                               float* __restrict__ out) {
  __shared__ float og[64];
  int g = blockIdx.x;
  if (threadIdx.x < 64) og[threadIdx.x] = outg[g*64+threadIdx.x];
  __syncthreads();
  int o = threadIdx.x;
  float acc = b[o];
  for (int k = 0; k < 64; ++k) acc += og[k]*W[o*64+k];
  out[g*128+o] = acc;
}

extern "C" void kernel_launch(void* const* d_in, const int* in_sizes, int n_in,
                              void* d_out, int out_size, void* d_ws, size_t ws_size,
                              hipStream_t stream) {
  const float* x_in     = (const float*)d_in[0];
  const int*   eidx     = (const int*)  d_in[1];
  const float* eattr    = (const float*)d_in[2];
  const int*   batch    = (const int*)  d_in[3];
  const float* lin1_w   = (const float*)d_in[4];
  const float* lin1_b   = (const float*)d_in[5];
  const float* g_lin1_w = (const float*)d_in[6];
  const float* g_att_l  = (const float*)d_in[7];
  const float* g_att_r  = (const float*)d_in[8];
  const float* g_lin2_w = (const float*)d_in[9];
  const float* g_bias   = (const float*)d_in[10];
  const float* gru0_wi  = (const float*)d_in[11];
  const float* gru0_wh  = (const float*)d_in[12];
  const float* gru0_bi  = (const float*)d_in[13];
  const float* gru0_bh  = (const float*)d_in[14];
  const float* conv_lin_w   = (const float*)d_in[15];
  const float* conv_att_src = (const float*)d_in[16];
  const float* conv_att_dst = (const float*)d_in[17];
  const float* conv_bias    = (const float*)d_in[18];
  const float* grul_wi  = (const float*)d_in[19];
  const float* grul_wh  = (const float*)d_in[20];
  const float* grul_bi  = (const float*)d_in[21];
  const float* grul_bh  = (const float*)d_in[22];
  const float* mol_lin_w    = (const float*)d_in[23];
  const float* mol_att_src  = (const float*)d_in[24];
  const float* mol_att_dst  = (const float*)d_in[25];
  const float* mol_bias     = (const float*)d_in[26];
  const float* mgru_wi  = (const float*)d_in[27];
  const float* mgru_wh  = (const float*)d_in[28];
  const float* mgru_bi  = (const float*)d_in[29];
  const float* mgru_bh  = (const float*)d_in[30];
  const float* lin2_w   = (const float*)d_in[31];
  const float* lin2_b   = (const float*)d_in[32];

  const int N64 = N_NODES*64;
  float* ws     = (float*)d_ws;
  float* xA     = ws;               // N*64
  float* xB     = xA + N64;         // N*64
  float* uy     = xB + N64;         // 2*N64: ubf2(uint2 N*16)+ypk(uint N*32) / hsb / ymol
  float* hagg   = uy + 2*N64;       // N*64
  float* sc1    = hagg + N64;       // N
  float* sc2    = sc1 + N_NODES;    // N
  float* pbuf   = sc2 + N_NODES;    // E (edge scores, ORIGINAL order)
  float* outg   = pbuf + N_EDGES;   // G*64
  int* bcnt   = (int*)(outg + NGRAPH*64); // NBKT
  int* rowptr = bcnt + N_NODES;     // N+2
  int2* binned = (int2*)(rowptr + N_NODES + 2); // E  (reused: mol partials)
  int2* sorted = binned + N_EDGES;  // E
  int* gstart = (int*)(sorted + N_EDGES); // G+1
  int* bstart = gstart + NGRAPH+1;  // NBKT+1
  int* bcur   = bstart + NBKT+1;    // NBKT
  unsigned short* wpk = (unsigned short*)(bcur + NBKT + 4); // 4 pairs * PAIR_C bf16

  uint2* ubf2 = (uint2*)uy;                        // N*16 uint2 (paired u)
  unsigned* ypk = (unsigned*)(uy + N64);           // N*32 packed y
  unsigned* hsb = (unsigned*)uy;                   // N*32 packed hs (reused after gate)

  float* part_acc = (float*)binned;                // G*8*64
  float* part_ss  = part_acc + NGRAPH*8*64;        // G*8
  float* addg     = part_ss + NGRAPH*8;            // G

  const int* src = eidx;
  const int* dst = eidx + N_EDGES;

  const int nbN4  = (N_NODES + 3)/4;
  const int nbN64 = (N_NODES + 63)/64;
  const int nbG4  = (NGRAPH + 3)/4;
  const int nbG8  = (NGRAPH*8 + 3)/4;
  const int nbES  = (N_EDGES/16 + 3)/4;   // escore: 16 edges per wave
  const int nbBIN = (N_EDGES + BIN_BLK-1)/BIN_BLK;

  // ---- bucket histogram + merged setup (scan + graph bounds) ----
  hipMemsetAsync(bcnt, 0, NBKT*sizeof(int), stream);
  k_bhist<<<nbBIN, 256, 0, stream>>>(dst, bcnt);
  k_setup<<<1, 512, 0, stream>>>(bcnt, bstart, bcur, rowptr + N_NODES, batch, gstart);

  // ---- GRU weight prepack (bf16, one launch) ----
  k_wpack4<<<(4*PAIR_C + 255)/256, 256, 0, stream>>>(gru0_wi, gru0_wh,
                                                     grul_wi, grul_wh,
                                                     grul_wi + 192*64, grul_wh + 192*64,
                                                     mgru_wi, mgru_wh, wpk);

  // ---- lin1 via MFMA (hi/lo split x, fused xr dot) ----
  k_lin1M<<<nbN64, 256, 0, stream>>>(x_in, lin1_w, lin1_b, g_att_r, xA, sc1);

  // ---- GATEConv: scores in original order, then locality-aware bin sort ----
  k_mmdualM<<<nbN64, 256, 0, stream>>>(xA, g_lin1_w, g_lin2_w, ubf2, ypk, N_NODES);
  k_escore<<<nbES, 256, 0, stream>>>(src, eattr, g_lin1_w, g_att_l, ubf2, pbuf);
  k_binA<<<nbBIN, 1024, 0, stream>>>(dst, src, pbuf, bcur, binned);
  k_binB<<<NBKT, 1024, 0, stream>>>(bstart, binned, sorted, rowptr);
  k_gate_agg<<<nbN4, 256, 0, stream>>>(rowptr, sorted, sc1, ypk, hagg);
  k_gruM<<<nbN64, 256, 0, stream>>>(hagg, g_bias, xA, wpk, wpk + 192*64,
                                    gru0_bi, gru0_bh, xB, N_NODES);

  float* xcur = xB; float* xoth = xA;

  // ---- GATConv layers ----
  for (int l = 0; l < 2; ++l) {
    k_mm64M<<<nbN64, 256, 0, stream>>>(xcur, conv_lin_w + l*64*64, 64, nullptr, hsb, N_NODES,
                                       conv_att_src + l*64, conv_att_dst + l*64, sc1, sc2, 0);
    k_conv_fused<<<nbN4, 256, 0, stream>>>(rowptr, sorted, sc1, sc2, hsb, hagg);
    k_gruM<<<nbN64, 256, 0, stream>>>(hagg, conv_bias + l*64, xcur,
                                      wpk + (1+l)*PAIR_C, wpk + (1+l)*PAIR_C + 192*64,
                                      grul_bi + l*192, grul_bh + l*192, xoth, N_NODES);
    float* t = xcur; xcur = xoth; xoth = t;
  }

  // ---- molecule readout (split-K over node slices) ----
  float* ymol = uy;
  k_molsum_p<<<nbG8, 256, 0, stream>>>(gstart, xcur, part_acc);
  k_molsum_c<<<nbG4, 256, 0, stream>>>(part_acc, outg);
  k_mm64M<<<nbN64, 256, 0, stream>>>(xcur, mol_lin_w, 64, ymol, nullptr, N_NODES,
                                     mol_att_src, nullptr, sc1, nullptr, 1);
  for (int t = 0; t < 2; ++t) {
    k_molhd<<<nbG4, 256, 0, stream>>>(outg, mol_lin_w, mol_att_dst, addg);
    k_molp<<<nbG8, 256, 0, stream>>>(gstart, addg, sc1, ymol, part_acc, part_ss);
    k_molc<<<nbG4, 256, 0, stream>>>(part_acc, part_ss, hagg);
    k_gruM<<<(NGRAPH+63)/64, 256, 0, stream>>>(hagg, mol_bias, outg,
                                               wpk + 3*PAIR_C, wpk + 3*PAIR_C + 192*64,
                                               mgru_bi, mgru_bh, outg, NGRAPH);
  }

  // ---- final linear ----
  k_final<<<NGRAPH, 128, 0, stream>>>(outg, lin2_w, lin2_b, (float*)d_out);
}

// Round 16
// 420.028 us; speedup vs baseline: 1.0180x; 1.0180x over previous
//
#include <hip/hip_runtime.h>
#include <math.h>

#define N_NODES 50000
#define N_EDGES 1000000
#define NGRAPH  512
#define INC     39
#define NBKT 196 // dst buckets of 256 nodes
#define BIN_BLK 4096
#define PAIR_C (2*192*64)

typedef __attribute__((ext_vector_type(8))) short bf16x8;
typedef __attribute__((ext_vector_type(4))) float f32x4;
typedef __attribute__((ext_vector_type(4))) int i32x4;

__device__ __forceinline__ float lrelu(float x){ return fmaxf(0.01f*x, x); }
__device__ __forceinline__ float fexp(float x){ return __builtin_amdgcn_exp2f(x*1.4426950408889634f); }
__device__ __forceinline__ float frcp(float x){ return __builtin_amdgcn_rcpf(x); }
__device__ __forceinline__ float eluf (float x){ return x > 0.f ? x : fexp(x) - 1.f; }
__device__ __forceinline__ float sigm (float x){ return frcp(1.f + fexp(-x)); }
__device__ __forceinline__ float ftanh(float x){
  x = fminf(fmaxf(x, -15.f), 15.f);
  float e = __builtin_amdgcn_exp2f(x*2.8853900817779268f); // exp(2x)
  return (e - 1.f)*frcp(e + 1.f);
}
__device__ __forceinline__ float rdlane(float v, int l){
  return __int_as_float(__builtin_amdgcn_readlane(__float_as_int(v), l));
}
__device__ __forceinline__ unsigned pk_bf16(float a, float b){
  unsigned r;
  asm volatile("v_cvt_pk_bf16_f32 %0, %1, %2" : "=v"(r) : "v"(a), "v"(b));
  return r;
}
__device__ __forceinline__ float bl(unsigned p){ return __uint_as_float(p << 16); }
__device__ __forceinline__ float bh(unsigned p){ return __uint_as_float(p & 0xffff0000u); }
__device__ __forceinline__ float tobf16f(float v){ return __uint_as_float(pk_bf16(v, 0.f) << 16); }

// ================= bucket histogram (196 coarse buckets) =================
__global__ __launch_bounds__(256) void k_bhist(const int* __restrict__ dst,
                                               int* __restrict__ bcnt) {
  __shared__ int h[NBKT];
  for (int i = threadIdx.x; i < NBKT; i += 256) h[i] = 0;
  __syncthreads();
  const int e0 = blockIdx.x * BIN_BLK;
  #pragma unroll 4
  for (int u = 0; u < 16; ++u) {
    int e = e0 + u*256 + threadIdx.x;
    if (e < N_EDGES) atomicAdd(&h[dst[e] >> 8], 1);
  }
  __syncthreads();
  for (int i = threadIdx.x; i < NBKT; i += 256) if (h[i]) atomicAdd(&bcnt[i], h[i]);
}

// ===== merged: bucket scan + bcur init + graph bounds =====
__global__ __launch_bounds__(512) void k_setup(const int* __restrict__ bcnt,
                                               int* __restrict__ bstart,
                                               int* __restrict__ bcur,
                                               int* __restrict__ rowptrN,
                                               const int* __restrict__ batch,
                                               int* __restrict__ gstart) {
  __shared__ int s[256];
  const int t = threadIdx.x;
  int v = 0;
  if (t < 256) { v = (t < NBKT) ? bcnt[t] : 0; s[t] = v; }
  __syncthreads();
  for (int off = 1; off < 256; off <<= 1) {
    int x = (t >= off && t < 256) ? s[t-off] : 0;
    __syncthreads();
    if (t < 256) s[t] += x;
    __syncthreads();
  }
  if (t < NBKT) { int st = s[t] - v; bstart[t] = st; bcur[t] = st; }
  if (t == 0) { bstart[NBKT] = N_EDGES; rowptrN[0] = N_EDGES; }
  int g = t;
  int lo = 0, hi = N_NODES;
  while (lo < hi) { int mid = (lo+hi)>>1; if (batch[mid] < g) lo = mid+1; else hi = mid; }
  gstart[g] = lo;
  if (g == 0) gstart[NGRAPH] = N_NODES;
}

// ===== Pass A: bin edges into 196 coarse buckets =====
__global__ __launch_bounds__(1024) void k_binA(const int* __restrict__ dst,
                                               const int* __restrict__ src,
                                               const float* __restrict__ p,
                                               int* __restrict__ bcur,
                                               int2* __restrict__ binned) {
  __shared__ int lcnt[NBKT];
  __shared__ int lbase[NBKT];
  __shared__ int gbase[NBKT];
  __shared__ int tmp[256];
  __shared__ int totsh;
  __shared__ int2 stage[BIN_BLK];
  const int t = threadIdx.x;
  const int e0 = blockIdx.x * BIN_BLK;
  for (int i = t; i < NBKT; i += 1024) lcnt[i] = 0;
  __syncthreads();
  int myb[4], myr[4], myd[4], mys[4]; float myp[4];
  #pragma unroll
  for (int u = 0; u < 4; ++u) {
    int e = e0 + u*1024 + t;
    if (e < N_EDGES) {
      int d = dst[e];
      myd[u] = d; mys[u] = src[e]; myp[u] = p[e];
      int b = d >> 8;
      myb[u] = b;
      myr[u] = atomicAdd(&lcnt[b], 1);
    } else myb[u] = -1;
  }
  __syncthreads();
  if (t < 256) tmp[t] = (t < NBKT) ? lcnt[t] : 0;
  __syncthreads();
  for (int off = 1; off < 256; off <<= 1) {
    int v = (t >= off && t < 256) ? tmp[t-off] : 0;
    __syncthreads();
    if (t < 256) tmp[t] += v;
    __syncthreads();
  }
  if (t < NBKT) lbase[t] = tmp[t] - lcnt[t];
  if (t == NBKT-1) totsh = tmp[t];
  if (t < NBKT && lcnt[t] > 0) gbase[t] = atomicAdd(&bcur[t], lcnt[t]);
  __syncthreads();
  #pragma unroll
  for (int u = 0; u < 4; ++u) {
    if (myb[u] >= 0) {
      int x = (mys[u] & 0xffff) | ((myd[u] & 255) << 16) | (myb[u] << 24);
      stage[lbase[myb[u]] + myr[u]] = make_int2(x, __float_as_int(myp[u]));
    }
  }
  __syncthreads();
  const int tot = totsh;
  for (int i = t; i < tot; i += 1024) {
    int2 r = stage[i];
    int b = (unsigned)r.x >> 24;
    binned[gbase[b] + (i - lbase[b])] = r;
  }
}

// ===== Pass B: per-bucket two-pass — build rowptr AND final CSR order =====
__global__ __launch_bounds__(1024) void k_binB(const int* __restrict__ bstart,
                                               const int2* __restrict__ binned,
                                               int2* __restrict__ sorted,
                                               int* __restrict__ rowptr) {
  __shared__ int lcnt[256];
  __shared__ int loc[256];
  const int b = blockIdx.x;
  const int base = bstart[b], end = bstart[b+1];
  const int t = threadIdx.x;
  if (t < 256) lcnt[t] = 0;
  __syncthreads();
  for (int i = base + t; i < end; i += 1024)
    atomicAdd(&lcnt[(binned[i].x >> 16) & 255], 1);
  __syncthreads();
  if (t < 256) loc[t] = lcnt[t];
  __syncthreads();
  for (int off = 1; off < 256; off <<= 1) {
    int v = (t >= off && t < 256) ? loc[t-off] : 0;
    __syncthreads();
    if (t < 256) loc[t] += v;
    __syncthreads();
  }
  if (t < 256) {
    int st = base + loc[t] - lcnt[t];
    loc[t] = st;
    int node = b*256 + t;
    if (node < N_NODES) rowptr[node] = st;
    lcnt[t] = 0;
  }
  __syncthreads();
  for (int i = base + t; i < end; i += 1024) {
    int2 r = binned[i];
    int dlow = (r.x >> 16) & 255;
    int rank = atomicAdd(&lcnt[dlow], 1);
    sorted[loc[dlow] + rank] = r;
  }
}

// ================= bf16 weight prepack: 4 GRU pairs in one launch =================
__global__ __launch_bounds__(256) void k_wpack4(const float* __restrict__ a0, const float* __restrict__ b0,
                                                const float* __restrict__ a1, const float* __restrict__ b1,
                                                const float* __restrict__ a2, const float* __restrict__ b2,
                                                const float* __restrict__ a3, const float* __restrict__ b3,
                                                unsigned short* __restrict__ o) {
  int i = blockIdx.x*256 + threadIdx.x;
  if (i >= 4*PAIR_C) return;
  int pair = i / PAIR_C;
  int r = i - pair*PAIR_C;
  bool hi = r >= 192*64;
  int rr = hi ? r - 192*64 : r;
  const float* s;
  if      (pair == 0) s = hi ? b0 : a0;
  else if (pair == 1) s = hi ? b1 : a1;
  else if (pair == 2) s = hi ? b2 : a2;
  else                s = hi ? b3 : a3;
  o[i] = (unsigned short)(pk_bf16(s[rr], 0.f) & 0xffffu);
}

// ===== MFMA lin1: wave = 16 nodes, K=39 padded; x split hi/lo bf16 =====
__global__ __launch_bounds__(256) void k_lin1M(const float* __restrict__ x,
                                               const float* __restrict__ W,  // [64][39]
                                               const float* __restrict__ b,
                                               const float* __restrict__ v1,
                                               float* __restrict__ out,
                                               float* __restrict__ o1) {
  const int lane = threadIdx.x & 63;
  const int l15 = lane & 15, lg = lane >> 4;
  const int n0 = blockIdx.x*64 + (threadIdx.x >> 6)*16;
  if (n0 >= N_NODES) return;
  union BF { bf16x8 v; unsigned u[4]; };
  BF Bf[3][4];
  #pragma unroll
  for (int c = 0; c < 3; ++c) {
    int kv0 = c*32 + lg*8;
    int off = (kv0 < 48) ? kv0 : (kv0 - 48);
    int cnt = 39 - off; cnt = cnt < 0 ? 0 : (cnt > 8 ? 8 : cnt);
    #pragma unroll
    for (int ct = 0; ct < 4; ++ct) {
      const float* wrow = W + (ct*16 + l15)*INC;
      float w8[8];
      #pragma unroll
      for (int j = 0; j < 8; ++j) w8[j] = (j < cnt) ? wrow[off+j] : 0.f;
      Bf[c][ct].u[0] = pk_bf16(w8[0], w8[1]);
      Bf[c][ct].u[1] = pk_bf16(w8[2], w8[3]);
      Bf[c][ct].u[2] = pk_bf16(w8[4], w8[5]);
      Bf[c][ct].u[3] = pk_bf16(w8[6], w8[7]);
    }
  }
  const int arow = n0 + l15;
  const bool av = arow < N_NODES;
  const float* xrow = x + (size_t)arow*INC;
  BF A[3];
  #pragma unroll
  for (int c = 0; c < 3; ++c) {
    int kv0 = c*32 + lg*8;
    int islo = (kv0 >= 48);
    int off = islo ? (kv0 - 48) : kv0;
    int cnt = 39 - off; cnt = cnt < 0 ? 0 : (cnt > 8 ? 8 : cnt);
    float a8[8];
    #pragma unroll
    for (int j = 0; j < 8; ++j) {
      float v = (av && j < cnt) ? xrow[off+j] : 0.f;
      if (islo) v = v - tobf16f(v);
      a8[j] = v;
    }
    A[c].u[0] = pk_bf16(a8[0], a8[1]);
    A[c].u[1] = pk_bf16(a8[2], a8[3]);
    A[c].u[2] = pk_bf16(a8[4], a8[5]);
    A[c].u[3] = pk_bf16(a8[6], a8[7]);
  }
  f32x4 acc[4];
  #pragma unroll
  for (int ct = 0; ct < 4; ++ct) acc[ct] = (f32x4){0.f,0.f,0.f,0.f};
  #pragma unroll
  for (int c = 0; c < 3; ++c)
    #pragma unroll
    for (int ct = 0; ct < 4; ++ct)
      acc[ct] = __builtin_amdgcn_mfma_f32_16x16x32_bf16(A[c].v, Bf[c][ct].v, acc[ct], 0, 0, 0);
  float bb[4], attv[4];
  #pragma unroll
  for (int ct = 0; ct < 4; ++ct) { bb[ct] = b[ct*16+l15]; attv[ct] = v1[ct*16+l15]; }
  #pragma unroll
  for (int reg = 0; reg < 4; ++reg) {
    const int node = n0 + 4*lg + reg;
    const bool nv = node < N_NODES;
    float pr = 0.f;
    #pragma unroll
    for (int ct = 0; ct < 4; ++ct) {
      float val = lrelu(acc[ct][reg] + bb[ct]);
      if (nv) out[(size_t)node*64 + ct*16 + l15] = val;
      pr = fmaf(val, attv[ct], pr);
    }
    pr += __shfl_xor(pr, 1, 64);
    pr += __shfl_xor(pr, 2, 64);
    pr += __shfl_xor(pr, 4, 64);
    pr += __shfl_xor(pr, 8, 64);
    if (l15 == 0 && nv) o1[node] = pr;
  }
}

// ===== MFMA dual matmul: u paired-dword layout + y packed =====
// ubf2 layout: uint2 per (node, l15): .x packs channels (l15, 32+l15), .y packs (16+l15, 48+l15)
__global__ __launch_bounds__(256) void k_mmdualM(const float* __restrict__ in,
                                                 const float* __restrict__ W1, // [64][80]
                                                 const float* __restrict__ W2, // [64][64]
                                                 uint2* __restrict__ ubf2,     // N*16 uint2
                                                 unsigned* __restrict__ ypk, int R) {
  const int lane = threadIdx.x & 63;
  const int l15 = lane & 15, lg = lane >> 4;
  const int n0 = blockIdx.x*64 + (threadIdx.x >> 6)*16;
  if (n0 >= R) return;
  union BF { bf16x8 v; unsigned u[4]; };
  BF B1[4][2], B2[4][2];
  #pragma unroll
  for (int ct = 0; ct < 4; ++ct) {
    #pragma unroll
    for (int c = 0; c < 2; ++c) {
      const float* w1 = W1 + (size_t)(ct*16 + l15)*80 + c*32 + lg*8;
      const float* w2 = W2 + (size_t)(ct*16 + l15)*64 + c*32 + lg*8;
      B1[ct][c].u[0] = pk_bf16(w1[0], w1[1]);
      B1[ct][c].u[1] = pk_bf16(w1[2], w1[3]);
      B1[ct][c].u[2] = pk_bf16(w1[4], w1[5]);
      B1[ct][c].u[3] = pk_bf16(w1[6], w1[7]);
      B2[ct][c].u[0] = pk_bf16(w2[0], w2[1]);
      B2[ct][c].u[1] = pk_bf16(w2[2], w2[3]);
      B2[ct][c].u[2] = pk_bf16(w2[4], w2[5]);
      B2[ct][c].u[3] = pk_bf16(w2[6], w2[7]);
    }
  }
  const int arow = n0 + l15;
  const bool av = arow < R;
  const float* xr = in + (size_t)arow*64;
  BF A[2];
  #pragma unroll
  for (int c = 0; c < 2; ++c) {
    const int k0 = c*32 + lg*8;
    float4 v0, v1;
    if (av) { v0 = *(const float4*)&xr[k0]; v1 = *(const float4*)&xr[k0+4]; }
    else    { v0 = v1 = make_float4(0.f,0.f,0.f,0.f); }
    A[c].u[0] = pk_bf16(v0.x, v0.y);
    A[c].u[1] = pk_bf16(v0.z, v0.w);
    A[c].u[2] = pk_bf16(v1.x, v1.y);
    A[c].u[3] = pk_bf16(v1.z, v1.w);
  }
  f32x4 aU[4], aY[4];
  #pragma unroll
  for (int ct = 0; ct < 4; ++ct) { aU[ct] = (f32x4){0.f,0.f,0.f,0.f}; aY[ct] = (f32x4){0.f,0.f,0.f,0.f}; }
  #pragma unroll
  for (int c = 0; c < 2; ++c)
    #pragma unroll
    for (int ct = 0; ct < 4; ++ct) {
      aU[ct] = __builtin_amdgcn_mfma_f32_16x16x32_bf16(A[c].v, B1[ct][c].v, aU[ct], 0, 0, 0);
      aY[ct] = __builtin_amdgcn_mfma_f32_16x16x32_bf16(A[c].v, B2[ct][c].v, aY[ct], 0, 0, 0);
    }
  #pragma unroll
  for (int reg = 0; reg < 4; ++reg) {
    const int node = n0 + 4*lg + reg;
    const bool nv = node < R;
    if (nv) {
      ubf2[(size_t)node*16 + l15] = make_uint2(pk_bf16(aU[0][reg], aU[2][reg]),
                                               pk_bf16(aU[1][reg], aU[3][reg]));
    }
    #pragma unroll
    for (int ct = 0; ct < 4; ++ct) {
      float yy = aY[ct][reg];
      float yp = __shfl_xor(yy, 1, 64);
      if (!(l15 & 1) && nv)
        ypk[(unsigned)node*32 + ct*8 + (l15>>1)] = pk_bf16(yy, yp);
    }
  }
}

// ===== MFMA mm64: [R,64]@W.T; optional fp32/packed out + dual dots; hilo for fp32-grade =====
__global__ __launch_bounds__(256) void k_mm64M(const float* __restrict__ in,
                                               const float* __restrict__ W, int rs,
                                               float* __restrict__ out,
                                               unsigned* __restrict__ outp, int R,
                                               const float* __restrict__ v1,
                                               const float* __restrict__ v2,
                                               float* __restrict__ o1,
                                               float* __restrict__ o2, int hilo) {
  const int lane = threadIdx.x & 63;
  const int l15 = lane & 15, lg = lane >> 4;
  const int n0 = blockIdx.x*64 + (threadIdx.x >> 6)*16;
  if (n0 >= R) return;
  union BF { bf16x8 v; unsigned u[4]; };
  BF Bf[4][2];
  #pragma unroll
  for (int ct = 0; ct < 4; ++ct) {
    #pragma unroll
    for (int c = 0; c < 2; ++c) {
      const float* w = W + (size_t)(ct*16 + l15)*rs + c*32 + lg*8;
      Bf[ct][c].u[0] = pk_bf16(w[0], w[1]);
      Bf[ct][c].u[1] = pk_bf16(w[2], w[3]);
      Bf[ct][c].u[2] = pk_bf16(w[4], w[5]);
      Bf[ct][c].u[3] = pk_bf16(w[6], w[7]);
    }
  }
  const int arow = n0 + l15;
  const bool av = arow < R;
  const float* xr = in + (size_t)arow*64;
  BF A[2], Alo[2];
  #pragma unroll
  for (int c = 0; c < 2; ++c) {
    const int k0 = c*32 + lg*8;
    float f[8];
    if (av) {
      float4 v0 = *(const float4*)&xr[k0];
      float4 v1l = *(const float4*)&xr[k0+4];
      f[0]=v0.x; f[1]=v0.y; f[2]=v0.z; f[3]=v0.w;
      f[4]=v1l.x; f[5]=v1l.y; f[6]=v1l.z; f[7]=v1l.w;
    } else {
      #pragma unroll
      for (int j = 0; j < 8; ++j) f[j] = 0.f;
    }
    A[c].u[0] = pk_bf16(f[0], f[1]);
    A[c].u[1] = pk_bf16(f[2], f[3]);
    A[c].u[2] = pk_bf16(f[4], f[5]);
    A[c].u[3] = pk_bf16(f[6], f[7]);
    if (hilo) {
      float l[8];
      #pragma unroll
      for (int j = 0; j < 8; ++j) l[j] = f[j] - tobf16f(f[j]);
      Alo[c].u[0] = pk_bf16(l[0], l[1]);
      Alo[c].u[1] = pk_bf16(l[2], l[3]);
      Alo[c].u[2] = pk_bf16(l[4], l[5]);
      Alo[c].u[3] = pk_bf16(l[6], l[7]);
    }
  }
  f32x4 acc[4];
  #pragma unroll
  for (int ct = 0; ct < 4; ++ct) acc[ct] = (f32x4){0.f,0.f,0.f,0.f};
  #pragma unroll
  for (int c = 0; c < 2; ++c)
    #pragma unroll
    for (int ct = 0; ct < 4; ++ct) {
      acc[ct] = __builtin_amdgcn_mfma_f32_16x16x32_bf16(A[c].v, Bf[ct][c].v, acc[ct], 0, 0, 0);
      if (hilo)
        acc[ct] = __builtin_amdgcn_mfma_f32_16x16x32_bf16(Alo[c].v, Bf[ct][c].v, acc[ct], 0, 0, 0);
    }
  float v1v[4], v2v[4];
  #pragma unroll
  for (int ct = 0; ct < 4; ++ct) {
    v1v[ct] = v1 ? v1[ct*16+l15] : 0.f;
    v2v[ct] = v2 ? v2[ct*16+l15] : 0.f;
  }
  #pragma unroll
  for (int reg = 0; reg < 4; ++reg) {
    const int node = n0 + 4*lg + reg;
    const bool nv = node < R;
    float pr1 = 0.f, pr2 = 0.f;
    #pragma unroll
    for (int ct = 0; ct < 4; ++ct) {
      float val = acc[ct][reg];
      if (out && nv) out[(size_t)node*64 + ct*16 + l15] = val;
      if (outp) {
        float partner = __shfl_xor(val, 1, 64);
        if (!(l15 & 1) && nv) outp[(unsigned)node*32 + ct*8 + (l15>>1)] = pk_bf16(val, partner);
      }
      pr1 = fmaf(val, v1v[ct], pr1);
      pr2 = fmaf(val, v2v[ct], pr2);
    }
    if (o1) {
      pr1 += __shfl_xor(pr1, 1, 64); pr2 += __shfl_xor(pr2, 1, 64);
      pr1 += __shfl_xor(pr1, 2, 64); pr2 += __shfl_xor(pr2, 2, 64);
      pr1 += __shfl_xor(pr1, 4, 64); pr2 += __shfl_xor(pr2, 4, 64);
      pr1 += __shfl_xor(pr1, 8, 64); pr2 += __shfl_xor(pr2, 8, 64);
      if (l15 == 0 && nv) { o1[node] = pr1; if (o2) o2[node] = pr2; }
    }
  }
}

// ===== GATE edge scores: wave = 64 edges, paired-dword u gathers, pipelined =====
__global__ __launch_bounds__(256) void k_escore(const int* __restrict__ srcarr,
                                                const float* __restrict__ ea,
                                                const float* __restrict__ glin1, // [64][80]
                                                const float* __restrict__ attl,
                                                const uint2* __restrict__ ubf2,
                                                float* __restrict__ pout) {
  const int lane = threadIdx.x & 63;
  const int l15 = lane & 15, lg = lane >> 4;
  const int gw = blockIdx.x*4 + (threadIdx.x >> 6);
  if (gw >= N_EDGES/64) return;
  float attlv[4];
  unsigned Bu[4][2];
  #pragma unroll
  for (int c = 0; c < 4; ++c) {
    const float4 b = *(const float4*)&glin1[(c*16 + l15)*80 + 64 + lg*4];
    Bu[c][0] = pk_bf16(b.x, b.y);
    Bu[c][1] = pk_bf16(b.z, b.w);
    attlv[c] = attl[c*16 + l15];
  }
  const int i0 = gw*64;
  i32x4 sv[4];
  #pragma unroll
  for (int it = 0; it < 4; ++it)
    sv[it] = *(const i32x4*)&srcarr[i0 + it*16 + 4*lg];
  f32x4 a[4];
  #pragma unroll
  for (int it = 0; it < 4; ++it)
    a[it] = __builtin_nontemporal_load((const f32x4*)&ea[(size_t)(i0 + it*16 + l15)*16 + lg*4]);
  uint2 ug0[4], ug1[4];
  #pragma unroll
  for (int r = 0; r < 4; ++r)
    ug0[r] = ubf2[(size_t)sv[0][r]*16 + l15];
  #pragma unroll
  for (int it = 0; it < 4; ++it) {
    if (it + 1 < 4) {
      #pragma unroll
      for (int r = 0; r < 4; ++r)
        ug1[r] = ubf2[(size_t)sv[it+1][r]*16 + l15];
    }
    union { bf16x8 v; unsigned u[4]; } A;
    A.u[0] = pk_bf16(a[it][0], a[it][1]);
    A.u[1] = pk_bf16(a[it][2], a[it][3]);
    A.u[2] = 0; A.u[3] = 0;
    float p[4] = {0.f,0.f,0.f,0.f};
    #pragma unroll
    for (int c = 0; c < 4; ++c) {
      union { bf16x8 v; unsigned u[4]; } B;
      B.u[0] = Bu[c][0]; B.u[1] = Bu[c][1]; B.u[2] = 0; B.u[3] = 0;
      f32x4 z = {0.f,0.f,0.f,0.f};
      f32x4 acc = __builtin_amdgcn_mfma_f32_16x16x32_bf16(A.v, B.v, z, 0, 0, 0);
      #pragma unroll
      for (int r = 0; r < 4; ++r) {
        float uu = (c == 0) ? bl(ug0[r].x) : (c == 1) ? bl(ug0[r].y)
                 : (c == 2) ? bh(ug0[r].x) : bh(ug0[r].y);
        float t = lrelu(uu + acc[r]);
        p[r] = fmaf(t, attlv[c], p[r]);
      }
    }
    #pragma unroll
    for (int r = 0; r < 4; ++r) {
      p[r] += __shfl_xor(p[r], 1, 64);
      p[r] += __shfl_xor(p[r], 2, 64);
      p[r] += __shfl_xor(p[r], 4, 64);
      p[r] += __shfl_xor(p[r], 8, 64);
    }
    if (l15 == 0) {
      f32x4 o = {p[0], p[1], p[2], p[3]};
      __builtin_nontemporal_store(o, (f32x4*)&pout[i0 + it*16 + 4*lg]);
    }
    #pragma unroll
    for (int r = 0; r < 4; ++r) ug0[r] = ug1[r];
  }
}

// ===== GATE aggregation: sorted records {src|dlow|bkt, p}, bf16-packed y gathers =====
__global__ __launch_bounds__(256) void k_gate_agg(const int* __restrict__ rowptr,
                                                  const int2* __restrict__ sorted,
                                                  const float* __restrict__ xr,
                                                  const unsigned* __restrict__ ypk,
                                                  float* __restrict__ hagg) {
  __shared__ int   sS[4][64];
  __shared__ float sE[4][64];
  const int w = __builtin_amdgcn_readfirstlane(threadIdx.x >> 6);
  const int lane = threadIdx.x & 63;
  const int slot = lane >> 5, l2 = lane & 31;
  const int d = blockIdx.x*4 + w;
  const int r0 = __builtin_amdgcn_readfirstlane(rowptr[d]);
  const int r1 = __builtin_amdgcn_readfirstlane(rowptr[d+1]);
  const float xrd = xr[d];
  float accx = 0.f, accy = 0.f, ssum = 0.f;
  for (int base = r0; base < r1; base += 64) {
    int i = base + lane;
    int cnt = r1 - base; if (cnt > 64) cnt = 64;
    float ev = 0.f; int s = 0;
    if (i < r1) {
      int2 r = sorted[i];
      s = r.x & 0xffff;
      ev = fexp(lrelu(__int_as_float(r.y) + xrd));
    }
    sS[w][lane] = s; sE[w][lane] = ev;
    ssum += ev;
    for (int jb = 0; jb < cnt; jb += 16) {
      float e8[8]; unsigned p8[8];
      #pragma unroll
      for (int u = 0; u < 8; ++u) {
        int jj = jb + 2*u + slot;
        int svv; float evv;
        if (jj < cnt) { svv = sS[w][jj]; evv = sE[w][jj]; }
        else          { svv = 0; evv = 0.f; }
        e8[u] = evv;
        p8[u] = ypk[(size_t)svv*32 + l2];
      }
      #pragma unroll
      for (int u = 0; u < 8; ++u) {
        accx = fmaf(e8[u], bl(p8[u]), accx);
        accy = fmaf(e8[u], bh(p8[u]), accy);
      }
    }
  }
  #pragma unroll
  for (int sh = 32; sh > 0; sh >>= 1) ssum += __shfl_xor(ssum, sh, 64);
  accx += __shfl_xor(accx, 32, 64);
  accy += __shfl_xor(accy, 32, 64);
  float rs = frcp(ssum + 1e-16f);
  if (slot == 0) *(float2*)&hagg[d*64 + 2*l2] = make_float2(accx*rs, accy*rs);
}

// ===== GATConv fused: 2 edges per wave, bf16-packed hs, sorted src =====
__global__ __launch_bounds__(256) void k_conv_fused(const int* __restrict__ rowptr,
                                                    const int2* __restrict__ sorted,
                                                    const float* __restrict__ asn,
                                                    const float* __restrict__ adn,
                                                    const unsigned* __restrict__ hsb,
                                                    float* __restrict__ hagg) {
  __shared__ int   sS[4][64];
  __shared__ float sE[4][64];
  const int w = __builtin_amdgcn_readfirstlane(threadIdx.x >> 6);
  const int lane = threadIdx.x & 63;
  const int slot = lane >> 5, l2 = lane & 31;
  const int d = blockIdx.x*4 + w;
  const int r0 = __builtin_amdgcn_readfirstlane(rowptr[d]);
  const int r1 = __builtin_amdgcn_readfirstlane(rowptr[d+1]);
  float adnd = adn[d];
  float accx = 0.f, accy = 0.f, ssum = 0.f;
  for (int base = r0; base < r1; base += 64) {
    int i = base + lane;
    int cnt = r1 - base; if (cnt > 64) cnt = 64;
    float ev = 0.f; int s = 0;
    if (i < r1) { s = sorted[i].x & 0xffff; ev = fexp(lrelu(asn[s] + adnd)); }
    sS[w][lane] = s; sE[w][lane] = ev;
    ssum += ev;
    for (int jb = 0; jb < cnt; jb += 16) {
      float e8[8]; unsigned p8[8];
      #pragma unroll
      for (int u = 0; u < 8; ++u) {
        int jj = jb + 2*u + slot;
        int svv; float evv;
        if (jj < cnt) { svv = sS[w][jj]; evv = sE[w][jj]; }
        else          { svv = 0; evv = 0.f; }
        e8[u] = evv;
        p8[u] = hsb[(size_t)svv*32 + l2];
      }
      #pragma unroll
      for (int u = 0; u < 8; ++u) {
        accx = fmaf(e8[u], bl(p8[u]), accx);
        accy = fmaf(e8[u], bh(p8[u]), accy);
      }
    }
  }
  #pragma unroll
  for (int sh = 32; sh > 0; sh >>= 1) ssum += __shfl_xor(ssum, sh, 64);
  accx += __shfl_xor(accx, 32, 64);
  accy += __shfl_xor(accy, 32, 64);
  float rs = frcp(ssum + 1e-16f);
  if (slot == 0) *(float2*)&hagg[d*64 + 2*l2] = make_float2(accx*rs, accy*rs);
}

// ===== MFMA GRU: out = relu(GRU(elu(inp+pbias), hid)), wave = 16 nodes =====
__global__ __launch_bounds__(256) void k_gruM(const float* __restrict__ inp,
                                              const float* __restrict__ pbias,
                                              const float* __restrict__ hid,
                                              const unsigned short* __restrict__ wibf,
                                              const unsigned short* __restrict__ whbf,
                                              const float* __restrict__ bi,
                                              const float* __restrict__ bh2,
                                              float* __restrict__ out, int R) {
  const int lane = threadIdx.x & 63;
  const int l15 = lane & 15, lg = lane >> 4;
  const int n0 = blockIdx.x*64 + (threadIdx.x >> 6)*16;
  if (n0 >= R) return;
  union BF { bf16x8 v; unsigned u[4]; };
  BF Ai[2], Ah[2];
  const int arow = n0 + l15;
  const bool av = arow < R;
  const float* ibase = inp + (size_t)arow*64;
  const float* hbase = hid + (size_t)arow*64;
  #pragma unroll
  for (int c = 0; c < 2; ++c) {
    const int k0 = c*32 + lg*8;
    float4 p0 = *(const float4*)&pbias[k0];
    float4 p1 = *(const float4*)&pbias[k0+4];
    float4 v0, v1, h0, h1;
    if (av) {
      v0 = *(const float4*)&ibase[k0];   v1 = *(const float4*)&ibase[k0+4];
      h0 = *(const float4*)&hbase[k0];   h1 = *(const float4*)&hbase[k0+4];
    } else {
      v0 = v1 = h0 = h1 = make_float4(0.f,0.f,0.f,0.f);
      p0 = p1 = make_float4(0.f,0.f,0.f,0.f);
    }
    Ai[c].u[0] = pk_bf16(eluf(v0.x+p0.x), eluf(v0.y+p0.y));
    Ai[c].u[1] = pk_bf16(eluf(v0.z+p0.z), eluf(v0.w+p0.w));
    Ai[c].u[2] = pk_bf16(eluf(v1.x+p1.x), eluf(v1.y+p1.y));
    Ai[c].u[3] = pk_bf16(eluf(v1.z+p1.z), eluf(v1.w+p1.w));
    Ah[c].u[0] = pk_bf16(h0.x, h0.y);
    Ah[c].u[1] = pk_bf16(h0.z, h0.w);
    Ah[c].u[2] = pk_bf16(h1.x, h1.y);
    Ah[c].u[3] = pk_bf16(h1.z, h1.w);
  }
  f32x4 rz[8], ni[4], nh[4];
  #pragma unroll
  for (int t = 0; t < 8; ++t) rz[t] = (f32x4){0.f,0.f,0.f,0.f};
  #pragma unroll
  for (int t = 0; t < 4; ++t) { ni[t] = (f32x4){0.f,0.f,0.f,0.f}; nh[t] = (f32x4){0.f,0.f,0.f,0.f}; }
  #pragma unroll
  for (int t = 0; t < 12; ++t) {
    BF Bi0, Bi1, Bh0, Bh1;
    const size_t off = ((size_t)(t*16 + l15))*64 + lg*8;
    Bi0.v = *(const bf16x8*)&wibf[off];
    Bi1.v = *(const bf16x8*)&wibf[off + 32];
    Bh0.v = *(const bf16x8*)&whbf[off];
    Bh1.v = *(const bf16x8*)&whbf[off + 32];
    if (t < 8) {
      f32x4 a = rz[t];
      a = __builtin_amdgcn_mfma_f32_16x16x32_bf16(Ai[0].v, Bi0.v, a, 0, 0, 0);
      a = __builtin_amdgcn_mfma_f32_16x16x32_bf16(Ai[1].v, Bi1.v, a, 0, 0, 0);
      a = __builtin_amdgcn_mfma_f32_16x16x32_bf16(Ah[0].v, Bh0.v, a, 0, 0, 0);
      a = __builtin_amdgcn_mfma_f32_16x16x32_bf16(Ah[1].v, Bh1.v, a, 0, 0, 0);
      rz[t] = a;
    } else {
      f32x4 a = ni[t-8];
      a = __builtin_amdgcn_mfma_f32_16x16x32_bf16(Ai[0].v, Bi0.v, a, 0, 0, 0);
      a = __builtin_amdgcn_mfma_f32_16x16x32_bf16(Ai[1].v, Bi1.v, a, 0, 0, 0);
      ni[t-8] = a;
      f32x4 b = nh[t-8];
      b = __builtin_amdgcn_mfma_f32_16x16x32_bf16(Ah[0].v, Bh0.v, b, 0, 0, 0);
      b = __builtin_amdgcn_mfma_f32_16x16x32_bf16(Ah[1].v, Bh1.v, b, 0, 0, 0);
      nh[t-8] = b;
    }
  }
  float bsum[8], binv[4], bhnv[4];
  #pragma unroll
  for (int t = 0; t < 8; ++t) bsum[t] = bi[t*16+l15] + bh2[t*16+l15];
  #pragma unroll
  for (int t = 0; t < 4; ++t) {
    binv[t] = bi[128 + t*16 + l15];
    bhnv[t] = bh2[128 + t*16 + l15];
  }
  #pragma unroll
  for (int reg = 0; reg < 4; ++reg) {
    const int node = n0 + 4*lg + reg;
    if (node >= R) continue;
    #pragma unroll
    for (int tt = 0; tt < 4; ++tt) {
      float r  = sigm(rz[tt][reg] + bsum[tt]);
      float z  = sigm(rz[4+tt][reg] + bsum[4+tt]);
      float nn = ftanh(ni[tt][reg] + binv[tt] + r*(nh[tt][reg] + bhnv[tt]));
      float hh = hid[(size_t)node*64 + tt*16 + l15];
      float o  = (1.f - z)*nn + z*hh;
      out[(size_t)node*64 + tt*16 + l15] = fmaxf(o, 0.f);
    }
  }
}

// ================= molecule readout, split-K (8 slices per graph) =================
__global__ __launch_bounds__(256) void k_molsum_p(const int* __restrict__ gstart,
                                                  const float* __restrict__ x,
                                                  float* __restrict__ part) {
  int idx = blockIdx.x*4 + (threadIdx.x>>6);
  if (idx >= NGRAPH*8) return;
  int g = idx >> 3, sl = idx & 7;
  int lane = threadIdx.x & 63;
  int n0 = gstart[g], n1 = gstart[g+1];
  int len = n1 - n0;
  int b0 = n0 + (len*sl >> 3), b1 = n0 + (len*(sl+1) >> 3);
  float acc = 0.f;
  for (int n = b0; n < b1; ++n) acc += x[n*64+lane];
  part[idx*64+lane] = acc;
}

__global__ __launch_bounds__(256) void k_molsum_c(const float* __restrict__ part,
                                                  float* __restrict__ outg) {
  int g = blockIdx.x*4 + (threadIdx.x>>6);
  if (g >= NGRAPH) return;
  int lane = threadIdx.x & 63;
  float a = 0.f;
  #pragma unroll
  for (int s = 0; s < 8; ++s) a += part[(g*8+s)*64+lane];
  outg[g*64+lane] = fmaxf(a, 0.f);
}

__global__ __launch_bounds__(256) void k_molhd(const float* __restrict__ outg,
                                               const float* __restrict__ W,
                                               const float* __restrict__ attd,
                                               float* __restrict__ addg) {
  __shared__ float wl[64*65];
  for (int idx = threadIdx.x; idx < 4096; idx += 256) wl[(idx>>6)*65+(idx&63)] = W[idx];
  __syncthreads();
  int g = blockIdx.x*4 + (threadIdx.x>>6);
  if (g >= NGRAPH) return;
  int lane = threadIdx.x & 63;
  float og = outg[g*64+lane];
  float hd = 0.f;
  #pragma unroll
  for (int k = 0; k < 64; ++k) hd += rdlane(og, k) * wl[lane*65+k];
  float p = hd * attd[lane];
  #pragma unroll
  for (int sh = 32; sh > 0; sh >>= 1) p += __shfl_xor(p, sh, 64);
  if (lane == 0) addg[g] = p;
}

__global__ __launch_bounds__(256) void k_molp(const int* __restrict__ gstart,
                                              const float* __restrict__ addg,
                                              const float* __restrict__ asn,
                                              const float* __restrict__ y,
                                              float* __restrict__ part_acc,
                                              float* __restrict__ part_ss) {
  int idx = blockIdx.x*4 + (threadIdx.x>>6);
  if (idx >= NGRAPH*8) return;
  int g = idx >> 3, sl = idx & 7;
  int lane = threadIdx.x & 63;
  int n0 = gstart[g], n1 = gstart[g+1];
  int len = n1 - n0;
  int b0 = n0 + (len*sl >> 3), b1 = n0 + (len*(sl+1) >> 3);
  float adg = addg[g];
  float acc = 0.f, ss = 0.f;
  for (int n = b0; n < b1; ++n) {
    float ev = fexp(lrelu(asn[n] + adg));
    acc += ev * y[n*64+lane];
    ss  += ev;
  }
  part_acc[idx*64+lane] = acc;
  if (lane == 0) part_ss[idx] = ss;
}

__global__ __launch_bounds__(256) void k_molc(const float* __restrict__ part_acc,
                                              const float* __restrict__ part_ss,
                                              float* __restrict__ hg) {
  int g = blockIdx.x*4 + (threadIdx.x>>6);
  if (g >= NGRAPH) return;
  int lane = threadIdx.x & 63;
  float a = 0.f, ss = 0.f;
  #pragma unroll
  for (int s = 0; s < 8; ++s) {
    a  += part_acc[(g*8+s)*64+lane];
    ss += part_ss[g*8+s];
  }
  hg[g*64+lane] = a * frcp(ss + 1e-16f);
}

__global__ __launch_bounds__(128) void k_final(const float* __restrict__ outg,
                                               const float* __restrict__ W,
                                               const float* __restrict__ b,
                                               float* __restrict__ out) {
  __shared__ float og[64];
  int g = blockIdx.x;
  if (threadIdx.x < 64) og[threadIdx.x] = outg[g*64+threadIdx.x];
  __syncthreads();
  int o = threadIdx.x;
  float acc = b[o];
  for (int k = 0; k < 64; ++k) acc += og[k]*W[o*64+k];
  out[g*128+o] = acc;
}

extern "C" void kernel_launch(void* const* d_in, const int* in_sizes, int n_in,
                              void* d_out, int out_size, void* d_ws, size_t ws_size,
                              hipStream_t stream) {
  const float* x_in     = (const float*)d_in[0];
  const int*   eidx     = (const int*)  d_in[1];
  const float* eattr    = (const float*)d_in[2];
  const int*   batch    = (const int*)  d_in[3];
  const float* lin1_w   = (const float*)d_in[4];
  const float* lin1_b   = (const float*)d_in[5];
  const float* g_lin1_w = (const float*)d_in[6];
  const float* g_att_l  = (const float*)d_in[7];
  const float* g_att_r  = (const float*)d_in[8];
  const float* g_lin2_w = (const float*)d_in[9];
  const float* g_bias   = (const float*)d_in[10];
  const float* gru0_wi  = (const float*)d_in[11];
  const float* gru0_wh  = (const float*)d_in[12];
  const float* gru0_bi  = (const float*)d_in[13];
  const float* gru0_bh  = (const float*)d_in[14];
  const float* conv_lin_w   = (const float*)d_in[15];
  const float* conv_att_src = (const float*)d_in[16];
  const float* conv_att_dst = (const float*)d_in[17];
  const float* conv_bias    = (const float*)d_in[18];
  const float* grul_wi  = (const float*)d_in[19];
  const float* grul_wh  = (const float*)d_in[20];
  const float* grul_bi  = (const float*)d_in[21];
  const float* grul_bh  = (const float*)d_in[22];
  const float* mol_lin_w    = (const float*)d_in[23];
  const float* mol_att_src  = (const float*)d_in[24];
  const float* mol_att_dst  = (const float*)d_in[25];
  const float* mol_bias     = (const float*)d_in[26];
  const float* mgru_wi  = (const float*)d_in[27];
  const float* mgru_wh  = (const float*)d_in[28];
  const float* mgru_bi  = (const float*)d_in[29];
  const float* mgru_bh  = (const float*)d_in[30];
  const float* lin2_w   = (const float*)d_in[31];
  const float* lin2_b   = (const float*)d_in[32];

  const int N64 = N_NODES*64;
  float* ws     = (float*)d_ws;
  float* xA     = ws;               // N*64
  float* xB     = xA + N64;         // N*64
  float* uy     = xB + N64;         // 2*N64: ubf2(uint2 N*16)+ypk(uint N*32) / hsb / ymol
  float* hagg   = uy + 2*N64;       // N*64
  float* sc1    = hagg + N64;       // N
  float* sc2    = sc1 + N_NODES;    // N
  float* pbuf   = sc2 + N_NODES;    // E (edge scores, ORIGINAL order)
  float* outg   = pbuf + N_EDGES;   // G*64
  int* bcnt   = (int*)(outg + NGRAPH*64); // NBKT
  int* rowptr = bcnt + N_NODES;     // N+2
  int2* binned = (int2*)(rowptr + N_NODES + 2); // E  (reused: mol partials)
  int2* sorted = binned + N_EDGES;  // E
  int* gstart = (int*)(sorted + N_EDGES); // G+1
  int* bstart = gstart + NGRAPH+1;  // NBKT+1
  int* bcur   = bstart + NBKT+1;    // NBKT
  unsigned short* wpk = (unsigned short*)(bcur + NBKT + 4); // 4 pairs * PAIR_C bf16

  uint2* ubf2 = (uint2*)uy;                        // N*16 uint2 (paired u)
  unsigned* ypk = (unsigned*)(uy + N64);           // N*32 packed y
  unsigned* hsb = (unsigned*)uy;                   // N*32 packed hs (reused after gate)

  float* part_acc = (float*)binned;                // G*8*64
  float* part_ss  = part_acc + NGRAPH*8*64;        // G*8
  float* addg     = part_ss + NGRAPH*8;            // G

  const int* src = eidx;
  const int* dst = eidx + N_EDGES;

  const int nbN4  = (N_NODES + 3)/4;
  const int nbN64 = (N_NODES + 63)/64;
  const int nbG4  = (NGRAPH + 3)/4;
  const int nbG8  = (NGRAPH*8 + 3)/4;
  const int nbES  = (N_EDGES/64 + 3)/4;   // escore: 64 edges per wave
  const int nbBIN = (N_EDGES + BIN_BLK-1)/BIN_BLK;

  // ---- bucket histogram + merged setup (scan + graph bounds) ----
  hipMemsetAsync(bcnt, 0, NBKT*sizeof(int), stream);
  k_bhist<<<nbBIN, 256, 0, stream>>>(dst, bcnt);
  k_setup<<<1, 512, 0, stream>>>(bcnt, bstart, bcur, rowptr + N_NODES, batch, gstart);

  // ---- GRU weight prepack (bf16, one launch) ----
  k_wpack4<<<(4*PAIR_C + 255)/256, 256, 0, stream>>>(gru0_wi, gru0_wh,
                                                     grul_wi, grul_wh,
                                                     grul_wi + 192*64, grul_wh + 192*64,
                                                     mgru_wi, mgru_wh, wpk);

  // ---- lin1 via MFMA (hi/lo split x, fused xr dot) ----
  k_lin1M<<<nbN64, 256, 0, stream>>>(x_in, lin1_w, lin1_b, g_att_r, xA, sc1);

  // ---- GATEConv: scores in original order, then locality-aware bin sort ----
  k_mmdualM<<<nbN64, 256, 0, stream>>>(xA, g_lin1_w, g_lin2_w, ubf2, ypk, N_NODES);
  k_escore<<<nbES, 256, 0, stream>>>(src, eattr, g_lin1_w, g_att_l, ubf2, pbuf);
  k_binA<<<nbBIN, 1024, 0, stream>>>(dst, src, pbuf, bcur, binned);
  k_binB<<<NBKT, 1024, 0, stream>>>(bstart, binned, sorted, rowptr);
  k_gate_agg<<<nbN4, 256, 0, stream>>>(rowptr, sorted, sc1, ypk, hagg);
  k_gruM<<<nbN64, 256, 0, stream>>>(hagg, g_bias, xA, wpk, wpk + 192*64,
                                    gru0_bi, gru0_bh, xB, N_NODES);

  float* xcur = xB; float* xoth = xA;

  // ---- GATConv layers ----
  for (int l = 0; l < 2; ++l) {
    k_mm64M<<<nbN64, 256, 0, stream>>>(xcur, conv_lin_w + l*64*64, 64, nullptr, hsb, N_NODES,
                                       conv_att_src + l*64, conv_att_dst + l*64, sc1, sc2, 0);
    k_conv_fused<<<nbN4, 256, 0, stream>>>(rowptr, sorted, sc1, sc2, hsb, hagg);
    k_gruM<<<nbN64, 256, 0, stream>>>(hagg, conv_bias + l*64, xcur,
                                      wpk + (1+l)*PAIR_C, wpk + (1+l)*PAIR_C + 192*64,
                                      grul_bi + l*192, grul_bh + l*192, xoth, N_NODES);
    float* t = xcur; xcur = xoth; xoth = t;
  }

  // ---- molecule readout (split-K over node slices) ----
  float* ymol = uy;
  k_molsum_p<<<nbG8, 256, 0, stream>>>(gstart, xcur, part_acc);
  k_molsum_c<<<nbG4, 256, 0, stream>>>(part_acc, outg);
  k_mm64M<<<nbN64, 256, 0, stream>>>(xcur, mol_lin_w, 64, ymol, nullptr, N_NODES,
                                     mol_att_src, nullptr, sc1, nullptr, 1);
  for (int t = 0; t < 2; ++t) {
    k_molhd<<<nbG4, 256, 0, stream>>>(outg, mol_lin_w, mol_att_dst, addg);
    k_molp<<<nbG8, 256, 0, stream>>>(gstart, addg, sc1, ymol, part_acc, part_ss);
    k_molc<<<nbG4, 256, 0, stream>>>(part_acc, part_ss, hagg);
    k_gruM<<<(NGRAPH+63)/64, 256, 0, stream>>>(hagg, mol_bias, outg,
                                               wpk + 3*PAIR_C, wpk + 3*PAIR_C + 192*64,
                                               mgru_bi, mgru_bh, outg, NGRAPH);
  }

  // ---- final linear ----
  k_final<<<NGRAPH, 128, 0, stream>>>(outg, lin2_w, lin2_b, (float*)d_out);
}